// Round 10
// baseline (329.896 us; speedup 1.0000x reference)
//
#include <hip/hip_runtime.h>
#include <stdint.h>

#define B_ 8
#define S_ 1024
#define DM_ 1024
#define H_ 16
#define DH_ 64
#define M_ (B_*S_)

typedef unsigned short u16;
typedef unsigned int u32;
typedef __attribute__((ext_vector_type(8))) short bf16x8;
typedef __attribute__((ext_vector_type(4))) float f32x4;

__device__ __forceinline__ u16 f2bf(float f){
  union { float f; u32 u; } x; x.f = f;
  u32 r = x.u + 0x7fffu + ((x.u >> 16) & 1u);
  return (u16)(r >> 16);
}
__device__ __forceinline__ float bf2f(u16 u){
  union { u32 u; float f; } x; x.u = ((u32)u) << 16; return x.f;
}
__device__ __forceinline__ u32 cvtpk(float lo, float hi){
  u32 r; asm("v_cvt_pk_bf16_f32 %0, %1, %2" : "=v"(r) : "v"(lo), "v"(hi)); return r;
}
__device__ __forceinline__ void gload16(const void* g, void* l){
  __builtin_amdgcn_global_load_lds((const __attribute__((address_space(1))) void*)g,
                                   (__attribute__((address_space(3))) void*)l, 16, 0, 0);
}

// ---------------- convert activations fp32 -> bf16 ----------------
__global__ void k_cvt_act(const float* __restrict__ v, const float* __restrict__ k,
                          const float* __restrict__ q, u16* __restrict__ vb,
                          u16* __restrict__ kb, u16* __restrict__ qb){
  int z = blockIdx.y;
  const float* src = (z == 0) ? v : (z == 1) ? k : q;
  u16* dst = (z == 0) ? vb : (z == 1) ? kb : qb;
  size_t i = ((size_t)blockIdx.x * blockDim.x + threadIdx.x) * 8;
  float4 a = *(const float4*)(src + i);
  float4 b = *(const float4*)(src + i + 4);
  uint4 o;
  o.x = (u32)f2bf(a.x) | ((u32)f2bf(a.y) << 16);
  o.y = (u32)f2bf(a.z) | ((u32)f2bf(a.w) << 16);
  o.z = (u32)f2bf(b.x) | ((u32)f2bf(b.y) << 16);
  o.w = (u32)f2bf(b.z) | ((u32)f2bf(b.w) << 16);
  *(uint4*)(dst + i) = o;
}

// -------- convert + transpose weights fp32[K][N] -> bf16[N][K]; z<4 into wall chunks --------
__global__ void k_cvt_wt(const float* __restrict__ w0, const float* __restrict__ w1,
                         const float* __restrict__ w2, const float* __restrict__ w3,
                         const float* __restrict__ w4,
                         u16* __restrict__ wall, u16* __restrict__ wot){
  __shared__ float tile[32][33];
  int z = blockIdx.z;
  const float* src = (z==0)?w0:(z==1)?w1:(z==2)?w2:(z==3)?w3:w4;
  u16* dst = (z<4) ? (wall + (size_t)z * 1048576) : wot;
  int n0 = blockIdx.x * 32, k0 = blockIdx.y * 32;
  int tx = threadIdx.x, ty = threadIdx.y;
#pragma unroll
  for (int i=0;i<4;i++) tile[ty+8*i][tx] = src[(size_t)(k0+ty+8*i)*DM_ + n0+tx];
  __syncthreads();
#pragma unroll
  for (int i=0;i<4;i++) dst[(size_t)(n0+ty+8*i)*DM_ + k0+tx] = f2bf(tile[tx][ty+8*i]);
}

// ======== fused projection GEMM, 256x256 tile, BK=64, 8-phase, one-phase-ahead ds_read ========
// Phase body: {STAGE; VMC (before loads!); PLOAD(next-phase frags); MFMA(current frags); BAR}.
// Fragment reads issue one phase before their MFMA -> lgkm latency hides under current MFMA
// cluster + barrier. VMC queue re-derived: VMC(8)@P2->X.A-h1, VMC(6)@P4->all Y,
// VMC(8)@P6->Y.A-h1, VMC(6)@P8->X.B+X.A-h0; prologue VMC(4); it==7 VMC(0)@P4.
__global__ __launch_bounds__(512, 2) void k_proj8(const u16* __restrict__ qb, const u16* __restrict__ kb,
                                                  const u16* __restrict__ vb, const u16* __restrict__ wall,
                                                  const float* __restrict__ bqp, const float* __restrict__ brp,
                                                  const float* __restrict__ bkp, const float* __restrict__ bvp,
                                                  u16* __restrict__ qpj, u16* __restrict__ rpj,
                                                  u16* __restrict__ kpj, u16* __restrict__ vtg){
  extern __shared__ u16 smem[];
  u16* As = smem;                 // [2][2][128][64]  (buf, half)
  u16* Bs = smem + 32768;         // [2][2][128][64]
  const int tid = threadIdx.x;
  const int w = tid >> 6, l = tid & 63, g = l >> 4, s = l & 15;
  const int wr = w >> 2, wc = w & 3;
  const int m0 = blockIdx.x << 8;
  const int ng0 = blockIdx.y << 8;
  const int chunk = ng0 >> 10;
  const u16* A = (chunk < 2) ? qb : (chunk == 2) ? kb : vb;

  u32 offA[2][2], offB[2][2];   // [half][i2]
#pragma unroll
  for (int h=0; h<2; h++)
#pragma unroll
    for (int i2=0; i2<2; i2++){
      int c = tid + i2*512; int rw = c >> 3, sl = c & 7;
      offA[h][i2] = (u32)((m0  + h*128 + rw) << 10) + ((sl ^ (rw & 7)) << 3);
      offB[h][i2] = (u32)((ng0 + h*128 + rw) << 10) + ((sl ^ (rw & 7)) << 3);
    }
  const u16* pA[2]; const u16* pB[2];
#pragma unroll
  for (int ks=0; ks<2; ks++){
    pA[ks] = &As[(wr*128 + s)*64 + (((ks*4+g) ^ (s & 7)) << 3)];
    pB[ks] = &Bs[(wc*64  + s)*64 + (((ks*4+g) ^ (s & 7)) << 3)];
  }

  f32x4 acc[8][4];
#pragma unroll
  for (int i=0;i<8;i++)
#pragma unroll
    for (int j=0;j<4;j++) acc[i][j] = (f32x4){0.f,0.f,0.f,0.f};

#define PSTAGE_A(buf, TCE, h) do { \
    gload16(Ak + offA[h][0] + (TCE), &As[(buf)*16384 + (h)*8192 + (w*64)*8]); \
    gload16(Ak + offA[h][1] + (TCE), &As[(buf)*16384 + (h)*8192 + (512 + w*64)*8]); \
  } while(0)

#define PSTAGE_B(buf, TCE, h) do { \
    gload16(Wk + offB[h][0] + (TCE), &Bs[(buf)*16384 + (h)*8192 + (w*64)*8]); \
    gload16(Wk + offB[h][1] + (TCE), &Bs[(buf)*16384 + (h)*8192 + (512 + w*64)*8]); \
  } while(0)

#define PLOADA(dst, cb, mh) do { \
    _Pragma("unroll") for (int mi2=0; mi2<4; mi2++) \
    _Pragma("unroll") for (int ks=0; ks<2; ks++) \
      dst[mi2][ks] = *(const bf16x8*)(pA[ks] + (cb)*16384 + (mh)*4096 + mi2*1024); \
    } while(0)

#define PLOADB(dst, cb, nh) do { \
    _Pragma("unroll") for (int ni2=0; ni2<2; ni2++) \
    _Pragma("unroll") for (int ks=0; ks<2; ks++) \
      dst[ni2][ks] = *(const bf16x8*)(pB[ks] + (cb)*16384 + (nh)*2048 + ni2*1024); \
    } while(0)

#define PMFMA(mh, nh, afr, bfr) do { \
    _Pragma("unroll") for (int mi2=0; mi2<4; mi2++) \
    _Pragma("unroll") for (int ni2=0; ni2<2; ni2++) \
    _Pragma("unroll") for (int ks=0; ks<2; ks++) \
      acc[(mh)*4+mi2][(nh)*2+ni2] = __builtin_amdgcn_mfma_f32_16x16x32_bf16( \
          afr[mi2][ks], bfr[ni2][ks], acc[(mh)*4+mi2][(nh)*2+ni2], 0, 0, 0); \
    } while(0)

#define BAR   __builtin_amdgcn_s_barrier()
#define PRIO1 __builtin_amdgcn_s_setprio(1)
#define PRIO0 __builtin_amdgcn_s_setprio(0)
#define VMC(N) asm volatile("s_waitcnt vmcnt(" #N ")" ::: "memory")

  bf16x8 aX0[4][2], aX1[4][2], aY0[4][2], aY1[4][2];
  bf16x8 bX0[2][2], bX1[2][2], bY0[2][2], bY1[2][2];

  // prologue: X <- tile0 (4 halves), Y <- tile1 B-halves; then preload P1 frags
  {
    const u16* Ak = A;  const u16* Wk = wall;
    PSTAGE_A(0, 0, 0); PSTAGE_A(0, 0, 1); PSTAGE_B(0, 0, 0); PSTAGE_B(0, 0, 1);
    PSTAGE_B(1, 64, 0); PSTAGE_B(1, 64, 1);
  }
  VMC(4);   // X fully landed
  BAR;
  PLOADA(aX0, 0, 0); PLOADB(bX0, 0, 0);

#pragma unroll 1
  for (int it = 0; it < 8; ++it){
    const u16* Ak = A + it*128;
    const u16* Wk = wall + it*128;
    const bool pre = (it < 7);
    // P1: stage Y.A-h0(t+1); load bX1 (P2); MFMA(0,0) aX0,bX0
    PSTAGE_A(1, 64, 0);
    PLOADB(bX1, 0, 1);
    PRIO1; PMFMA(0, 0, aX0, bX0); PRIO0; BAR;
    // P2: stage Y.A-h1; VMC(8) [X.A-h1 landed]; load aX1 (P3); MFMA(0,1) aX0,bX1
    PSTAGE_A(1, 64, 1);
    VMC(8);
    PLOADA(aX1, 0, 1);
    PRIO1; PMFMA(0, 1, aX0, bX1); PRIO0; BAR;
    // P3: stage X.B-h0(t+2); MFMA(1,1) aX1,bX1
    if (pre) PSTAGE_B(0, 128, 0);
    PRIO1; PMFMA(1, 1, aX1, bX1); PRIO0; BAR;
    // P4: stage X.B-h1(t+2); VMC(6|0) [all Y landed]; load aY0,bY0 (P5); MFMA(1,0) aX1,bX0
    if (pre) PSTAGE_B(0, 128, 1);
    if (it == 7) VMC(0); else VMC(6);
    PLOADA(aY0, 1, 0); PLOADB(bY0, 1, 0);
    PRIO1; PMFMA(1, 0, aX1, bX0); PRIO0; BAR;
    // P5: stage X.A-h0(t+2); load bY1 (P6); MFMA(0,0) aY0,bY0
    if (pre) PSTAGE_A(0, 128, 0);
    PLOADB(bY1, 1, 1);
    PRIO1; PMFMA(0, 0, aY0, bY0); PRIO0; BAR;
    // P6: stage X.A-h1; VMC(8) [Y.A-h1 landed]; load aY1 (P7); MFMA(0,1) aY0,bY1
    if (pre) PSTAGE_A(0, 128, 1);
    VMC(8);
    PLOADA(aY1, 1, 1);
    PRIO1; PMFMA(0, 1, aY0, bY1); PRIO0; BAR;
    // P7: stage Y.B-h0(t+3); MFMA(1,1) aY1,bY1
    if (pre) PSTAGE_B(1, 192, 0);
    PRIO1; PMFMA(1, 1, aY1, bY1); PRIO0; BAR;
    // P8: stage Y.B-h1(t+3); VMC(6) [X.B+X.A-h0 landed]; load aX0,bX0 (next P1); MFMA(1,0)
    if (pre) PSTAGE_B(1, 192, 1);
    if (pre){
      VMC(6);
      PLOADA(aX0, 0, 0); PLOADB(bX0, 0, 0);
    }
    PRIO1; PMFMA(1, 0, aY1, bY0); PRIO0; BAR;
  }

  const float* bias = (chunk==0)?bqp:(chunk==1)?brp:(chunk==2)?bkp:bvp;
  u16* outp = (chunk==0)?qpj:(chunk==1)?rpj:kpj;
#pragma unroll
  for (int ni=0; ni<4; ni++){
    int cg = ng0 + wc*64 + ni*16 + s;
    int col = cg & 1023;
    float bv = bias[col];
#pragma unroll
    for (int mi=0; mi<8; mi++){
      int row = m0 + wr*128 + mi*16 + g*4;
      if (chunk == 3){
        union { short4 v; u16 e[4]; } pk2;
#pragma unroll
        for (int r=0;r<4;r++) pk2.e[r] = f2bf(acc[mi][ni][r] + bv);
        size_t vrow = ((size_t)(row >> 10) * 16 + (col >> 6)) * 64 + (col & 63);
        *(short4*)&vtg[(vrow << 10) + (row & 1023)] = pk2.v;
      } else {
#pragma unroll
        for (int r=0;r<4;r++)
          outp[((size_t)(row+r) << 10) + col] = f2bf(acc[mi][ni][r] + bv);
      }
    }
  }
#undef PSTAGE_A
#undef PSTAGE_B
#undef PLOADA
#undef PLOADB
#undef PMFMA
#undef BAR
#undef PRIO1
#undef PRIO0
#undef VMC
}

// ---------------- output GEMM: Out[M][1024] = A @ Bt^T + bias (f32 out) ----------------
__global__ __launch_bounds__(256) void k_gemm_out(const u16* __restrict__ A, const u16* __restrict__ Bt,
                                                  const float* __restrict__ bias, float* __restrict__ Out){
  __shared__ u16 As[128*64];
  __shared__ u16 Bs[128*64];
  const int tid = threadIdx.x;
  const int w = tid >> 6, l = tid & 63, g = l >> 4, s = l & 15;
  const int wr = w >> 1, wc = w & 1;
  const int m0 = blockIdx.x << 7, n0 = blockIdx.y << 7;
  f32x4 acc[4][4];
#pragma unroll
  for (int i=0;i<4;i++)
#pragma unroll
    for (int j=0;j<4;j++) acc[i][j] = (f32x4){0.f,0.f,0.f,0.f};

  for (int k0 = 0; k0 < 1024; k0 += 64){
    __syncthreads();
#pragma unroll
    for (int i=0;i<4;i++){
      int c = tid + i*256;
      int m = c >> 3, slot = c & 7;
      gload16(A + ((size_t)(m0+m) << 10) + (k0 + ((slot ^ (m & 7)) << 3)),
              &As[(i*256 + w*64) * 8]);
    }
#pragma unroll
    for (int i=0;i<4;i++){
      int c = tid + i*256;
      int n = c >> 3, slot = c & 7;
      gload16(Bt + ((size_t)(n0+n) << 10) + (k0 + ((slot ^ (n & 7)) << 3)),
              &Bs[(i*256 + w*64) * 8]);
    }
    __syncthreads();
#pragma unroll
    for (int ks=0; ks<2; ks++){
      bf16x8 af[4], bfv[4];
#pragma unroll
      for (int mi=0;mi<4;mi++){
        int m = wr*64 + mi*16 + s;
        af[mi] = *(const bf16x8*)&As[m*64 + (((ks*4+g) ^ (s & 7)) << 3)];
      }
#pragma unroll
      for (int ni=0;ni<4;ni++){
        int n = wc*64 + ni*16 + s;
        bfv[ni] = *(const bf16x8*)&Bs[n*64 + (((ks*4+g) ^ (s & 7)) << 3)];
      }
#pragma unroll
      for (int mi=0;mi<4;mi++)
#pragma unroll
        for (int ni=0;ni<4;ni++)
          acc[mi][ni] = __builtin_amdgcn_mfma_f32_16x16x32_bf16(af[mi], bfv[ni], acc[mi][ni], 0, 0, 0);
    }
  }
#pragma unroll
  for (int ni=0;ni<4;ni++){
    int col = n0 + wc*64 + ni*16 + s;
    float bv = bias[col];
#pragma unroll
    for (int mi=0;mi<4;mi++){
      int row = m0 + wr*64 + mi*16 + g*4;
#pragma unroll
      for (int r=0;r<4;r++)
        Out[((size_t)(row+r) << 10) + col] = acc[mi][ni][r] + bv;
    }
  }
}

// ------- flash attention + R-gating: QBLK=128 (8 waves), swapped QK^T, dbuf, defer-max -------
__global__ __launch_bounds__(512) void k_attn(const u16* __restrict__ qp, const u16* __restrict__ kp,
                                              const u16* __restrict__ vtg, const u16* __restrict__ rp,
                                              u16* __restrict__ gated){
  __shared__ u16 Ks[2][64*64];     // [sj][d], k-slot XOR-swizzled
  __shared__ u16 Vs[2][64*64];     // [d][sj], sj-slot XOR-swizzled
  __shared__ u32 PsU[8*16*32];     // per-wave P rows, XOR-banked
  const int tid = threadIdx.x;
  const int w = tid >> 6, l = tid & 63, g = l >> 4, s = l & 15;
  const int bid = blockIdx.x;
  const int swz = (bid & 7) * 128 + (bid >> 3);   // XCD-bijective (1024 % 8 == 0)
  const int bh = swz >> 3;
  const int q0 = (swz & 7) << 7;
  const int b = bh >> 4, h = bh & 15;
  const size_t base = ((size_t)b << 20);
  const int colh = h << 6;
  const float KL = 1.4426950408889634f / 32.0f;

  const size_t qoff = base + ((size_t)(q0 + w*16 + s) << 10) + colh;
  bf16x8 qf0 = *(const bf16x8*)(qp + qoff + g*8);
  bf16x8 qf1 = *(const bf16x8*)(qp + qoff + 32 + g*8);
  const size_t vbase = ((size_t)(b*16 + h)) << 16;

  u32* PsW = PsU + (w << 9);
  const int sx2 = s << 1;

  const int rr = tid >> 3, sl = tid & 7;
  const u32 koff = (u32)(rr << 10) + colh + ((sl ^ (rr & 7)) << 3);
  const u32 voff = (u32)(rr << 10) + ((sl ^ (rr & 7)) << 3);
  const u16* kbgl = kp + base;
  const u16* vbgl = vtg + vbase;

  float mrun = -1e30f, lsum = 0.f;
  f32x4 of[4];
#pragma unroll
  for (int d=0;d<4;d++) of[d] = (f32x4){0.f,0.f,0.f,0.f};

#define STAGE_KV(BUF, KV0) do { \
    gload16(kbgl + ((u32)(KV0) << 10) + koff, &Ks[BUF][(w*64)*8]); \
    gload16(vbgl + (KV0) + voff, &Vs[BUF][(w*64)*8]); \
  } while(0)

  STAGE_KV(0, 0);
  __syncthreads();

  int cur = 0;
  for (int t = 0; t < 16; t++){
    if (t < 15) STAGE_KV(cur ^ 1, (t+1) << 6);
    const u16* ksb = Ks[cur];
    const u16* vsb = Vs[cur];

    f32x4 e2[4];
#pragma unroll
    for (int sjf=0;sjf<4;sjf++){
      e2[sjf] = (f32x4){0.f,0.f,0.f,0.f};
      int sj = sjf*16 + s;
      bf16x8 kf0 = *(const bf16x8*)&ksb[sj*64 + ((g ^ (s & 7)) << 3)];
      e2[sjf] = __builtin_amdgcn_mfma_f32_16x16x32_bf16(kf0, qf0, e2[sjf], 0, 0, 0);
      bf16x8 kf1 = *(const bf16x8*)&ksb[sj*64 + (((4+g) ^ (s & 7)) << 3)];
      e2[sjf] = __builtin_amdgcn_mfma_f32_16x16x32_bf16(kf1, qf1, e2[sjf], 0, 0, 0);
    }
    float rm = fmaxf(fmaxf(e2[0][0], e2[0][1]), e2[0][2]);
    rm = fmaxf(fmaxf(rm, e2[0][3]), e2[1][0]);
    rm = fmaxf(fmaxf(rm, e2[1][1]), e2[1][2]);
    rm = fmaxf(fmaxf(rm, e2[1][3]), e2[2][0]);
    rm = fmaxf(fmaxf(rm, e2[2][1]), e2[2][2]);
    rm = fmaxf(fmaxf(rm, e2[2][3]), e2[3][0]);
    rm = fmaxf(fmaxf(rm, e2[3][1]), e2[3][2]);
    rm = fmaxf(rm, e2[3][3]);
    rm = fmaxf(rm, __shfl_xor(rm, 16, 64));
    rm = fmaxf(rm, __shfl_xor(rm, 32, 64));
    if (!__all(rm <= mrun + 177.0f)){
      float nm = fmaxf(mrun, rm);
      float alpha = __builtin_amdgcn_exp2f((mrun - nm) * KL);
      mrun = nm;
      lsum *= alpha;
      float ac[4];
#pragma unroll
      for (int r=0;r<4;r++) ac[r] = __shfl(alpha, g*4 + r, 64);
#pragma unroll
      for (int d=0; d<4; d++)
#pragma unroll
        for (int r=0;r<4;r++) of[d][r] *= ac[r];
    }

    const float mk = mrun * KL;
#pragma unroll
    for (int sjf=0;sjf<4;sjf++){
      float p0 = __builtin_amdgcn_exp2f(e2[sjf][0]*KL - mk);
      float p1 = __builtin_amdgcn_exp2f(e2[sjf][1]*KL - mk);
      float p2 = __builtin_amdgcn_exp2f(e2[sjf][2]*KL - mk);
      float p3 = __builtin_amdgcn_exp2f(e2[sjf][3]*KL - mk);
      lsum += (p0 + p1) + (p2 + p3);
      uint2 pk; pk.x = cvtpk(p0, p1); pk.y = cvtpk(p2, p3);
      int phys = (8*sjf + 2*g) ^ sx2;
      *reinterpret_cast<uint2*>(&PsW[(s << 5) + phys]) = pk;
    }
    union { u32 u[4]; bf16x8 v; } pa0, pa1;
    {
      uint2 r0 = *reinterpret_cast<const uint2*>(&PsW[(s << 5) + ((4*g    ) ^ sx2)]);
      uint2 r1 = *reinterpret_cast<const uint2*>(&PsW[(s << 5) + ((4*g + 2) ^ sx2)]);
      pa0.u[0] = r0.x; pa0.u[1] = r0.y; pa0.u[2] = r1.x; pa0.u[3] = r1.y;
      uint2 r2 = *reinterpret_cast<const uint2*>(&PsW[(s << 5) + ((16 + 4*g    ) ^ sx2)]);
      uint2 r3 = *reinterpret_cast<const uint2*>(&PsW[(s << 5) + ((16 + 4*g + 2) ^ sx2)]);
      pa1.u[0] = r2.x; pa1.u[1] = r2.y; pa1.u[2] = r3.x; pa1.u[3] = r3.y;
    }
#pragma unroll
    for (int df=0; df<4; df++){
      int d = df*16 + s;
      bf16x8 v0 = *(const bf16x8*)&vsb[d*64 + ((g ^ (s & 7)) << 3)];
      bf16x8 v1 = *(const bf16x8*)&vsb[d*64 + (((4+g) ^ (s & 7)) << 3)];
      of[df] = __builtin_amdgcn_mfma_f32_16x16x32_bf16(pa0.v, v0, of[df], 0, 0, 0);
      of[df] = __builtin_amdgcn_mfma_f32_16x16x32_bf16(pa1.v, v1, of[df], 0, 0, 0);
    }
    __syncthreads();
    cur ^= 1;
  }
#undef STAGE_KV

  lsum += __shfl_xor(lsum, 16, 64);
  lsum += __shfl_xor(lsum, 32, 64);
  float inv = 1.0f / lsum;
  float ic[4];
#pragma unroll
  for (int r=0;r<4;r++) ic[r] = __shfl(inv, g*4 + r, 64);
#pragma unroll
  for (int df=0; df<4; df++){
#pragma unroll
    for (int r=0;r<4;r++){
      size_t row = (size_t)(q0 + w*16 + g*4 + r);
      size_t idx = base + (row << 10) + colh + df*16 + s;
      float o = of[df][r] * ic[r];
      float rg = bf2f(rp[idx]);
      gated[idx] = f2bf(o * rg);
    }
  }
}

extern "C" void kernel_launch(void* const* d_in, const int* in_sizes, int n_in,
                              void* d_out, int out_size, void* d_ws, size_t ws_size,
                              hipStream_t stream){
  (void)in_sizes; (void)n_in; (void)out_size; (void)ws_size;
  const float* value = (const float*)d_in[0];
  const float* key   = (const float*)d_in[1];
  const float* query = (const float*)d_in[2];
  const float* Wq = (const float*)d_in[3];  const float* bq = (const float*)d_in[4];
  const float* Wk = (const float*)d_in[5];  const float* bk = (const float*)d_in[6];
  const float* Wv = (const float*)d_in[7];  const float* bv = (const float*)d_in[8];
  const float* Wr = (const float*)d_in[9];  const float* br = (const float*)d_in[10];
  const float* Wo = (const float*)d_in[11]; const float* bo = (const float*)d_in[12];

  char* ws = (char*)d_ws;
  const size_t MB = (size_t)1 << 20;
  u16* qb   = (u16*)(ws + 0*MB);
  u16* kb   = (u16*)(ws + 16*MB);
  u16* vb   = (u16*)(ws + 32*MB);
  u16* wall = (u16*)(ws + 48*MB);    // 8 MB: [Wq^T | Wr^T | Wk^T | Wv^T] bf16 [4096][1024]
  u16* wot  = (u16*)(ws + 56*MB);
  u16* qpj  = (u16*)(ws + 58*MB);
  u16* kpj  = (u16*)(ws + 74*MB);
  u16* vtg  = (u16*)(ws + 90*MB);    // V projection, pre-transposed [(b*16+h)*64+d][sq]
  u16* rpj  = (u16*)(ws + 106*MB);
  u16* gat  = qb;

  (void)hipFuncSetAttribute(reinterpret_cast<const void*>(&k_proj8),
                            hipFuncAttributeMaxDynamicSharedMemorySize, 131072);

  k_cvt_act<<<dim3(4096, 3), 256, 0, stream>>>(value, key, query, vb, kb, qb);
  k_cvt_wt<<<dim3(32, 32, 5), dim3(32, 8), 0, stream>>>(Wq, Wr, Wk, Wv, Wo, wall, wot);
  k_proj8<<<dim3(32, 16), 512, 131072, stream>>>(qb, kb, vb, wall, bq, br, bk, bv,
                                                 qpj, rpj, kpj, vtg);
  k_attn<<<1024, 512, 0, stream>>>(qpj, kpj, vtg, rpj, gat);
  k_gemm_out<<<dim3(64, 8), 256, 0, stream>>>(gat, wot, bo, (float*)d_out);
}

// Round 12
// 206.203 us; speedup vs baseline: 1.5999x; 1.5999x over previous
//
#include <hip/hip_runtime.h>
#include <stdint.h>

#define B_ 8
#define S_ 1024
#define DM_ 1024
#define H_ 16
#define DH_ 64
#define M_ (B_*S_)

typedef unsigned short u16;
typedef unsigned int u32;
typedef __attribute__((ext_vector_type(8))) short bf16x8;
typedef __attribute__((ext_vector_type(4))) float f32x4;

__device__ __forceinline__ u16 f2bf(float f){
  union { float f; u32 u; } x; x.f = f;
  u32 r = x.u + 0x7fffu + ((x.u >> 16) & 1u);
  return (u16)(r >> 16);
}
__device__ __forceinline__ float bf2f(u16 u){
  union { u32 u; float f; } x; x.u = ((u32)u) << 16; return x.f;
}
__device__ __forceinline__ u32 cvtpk(float lo, float hi){
  u32 r; asm("v_cvt_pk_bf16_f32 %0, %1, %2" : "=v"(r) : "v"(lo), "v"(hi)); return r;
}
__device__ __forceinline__ void gload16(const void* g, void* l){
  __builtin_amdgcn_global_load_lds((const __attribute__((address_space(1))) void*)g,
                                   (__attribute__((address_space(3))) void*)l, 16, 0, 0);
}

// ---------------- convert activations fp32 -> bf16 ----------------
__global__ void k_cvt_act(const float* __restrict__ v, const float* __restrict__ k,
                          const float* __restrict__ q, u16* __restrict__ vb,
                          u16* __restrict__ kb, u16* __restrict__ qb){
  int z = blockIdx.y;
  const float* src = (z == 0) ? v : (z == 1) ? k : q;
  u16* dst = (z == 0) ? vb : (z == 1) ? kb : qb;
  size_t i = ((size_t)blockIdx.x * blockDim.x + threadIdx.x) * 8;
  float4 a = *(const float4*)(src + i);
  float4 b = *(const float4*)(src + i + 4);
  uint4 o;
  o.x = (u32)f2bf(a.x) | ((u32)f2bf(a.y) << 16);
  o.y = (u32)f2bf(a.z) | ((u32)f2bf(a.w) << 16);
  o.z = (u32)f2bf(b.x) | ((u32)f2bf(b.y) << 16);
  o.w = (u32)f2bf(b.z) | ((u32)f2bf(b.w) << 16);
  *(uint4*)(dst + i) = o;
}

// -------- convert + transpose weights fp32[K][N] -> bf16[N][K]; z<4 into wall chunks --------
__global__ void k_cvt_wt(const float* __restrict__ w0, const float* __restrict__ w1,
                         const float* __restrict__ w2, const float* __restrict__ w3,
                         const float* __restrict__ w4,
                         u16* __restrict__ wall, u16* __restrict__ wot){
  __shared__ float tile[32][33];
  int z = blockIdx.z;
  const float* src = (z==0)?w0:(z==1)?w1:(z==2)?w2:(z==3)?w3:w4;
  u16* dst = (z<4) ? (wall + (size_t)z * 1048576) : wot;
  int n0 = blockIdx.x * 32, k0 = blockIdx.y * 32;
  int tx = threadIdx.x, ty = threadIdx.y;
#pragma unroll
  for (int i=0;i<4;i++) tile[ty+8*i][tx] = src[(size_t)(k0+ty+8*i)*DM_ + n0+tx];
  __syncthreads();
#pragma unroll
  for (int i=0;i<4;i++) dst[(size_t)(n0+ty+8*i)*DM_ + k0+tx] = f2bf(tile[tx][ty+8*i]);
}

// ======== fused projection GEMM, 256x256 tile, BK=64, 8-phase, ONE barrier per phase ========
// (Round-8 version — measured 85.9 us; schedule variants all null/regressed.)
__global__ __launch_bounds__(512, 2) void k_proj8(const u16* __restrict__ qb, const u16* __restrict__ kb,
                                                  const u16* __restrict__ vb, const u16* __restrict__ wall,
                                                  const float* __restrict__ bqp, const float* __restrict__ brp,
                                                  const float* __restrict__ bkp, const float* __restrict__ bvp,
                                                  u16* __restrict__ qpj, u16* __restrict__ rpj,
                                                  u16* __restrict__ kpj, u16* __restrict__ vtg){
  extern __shared__ u16 smem[];
  u16* As = smem;                 // [2][2][128][64]  (buf, half)
  u16* Bs = smem + 32768;         // [2][2][128][64]
  const int tid = threadIdx.x;
  const int w = tid >> 6, l = tid & 63, g = l >> 4, s = l & 15;
  const int wr = w >> 2, wc = w & 3;
  const int m0 = blockIdx.x << 8;
  const int ng0 = blockIdx.y << 8;
  const int chunk = ng0 >> 10;
  const u16* A = (chunk < 2) ? qb : (chunk == 2) ? kb : vb;

  u32 offA[2][2], offB[2][2];   // [half][i2]
#pragma unroll
  for (int h=0; h<2; h++)
#pragma unroll
    for (int i2=0; i2<2; i2++){
      int c = tid + i2*512; int rw = c >> 3, sl = c & 7;
      offA[h][i2] = (u32)((m0  + h*128 + rw) << 10) + ((sl ^ (rw & 7)) << 3);
      offB[h][i2] = (u32)((ng0 + h*128 + rw) << 10) + ((sl ^ (rw & 7)) << 3);
    }
  const u16* pA[2]; const u16* pB[2];
#pragma unroll
  for (int ks=0; ks<2; ks++){
    pA[ks] = &As[(wr*128 + s)*64 + (((ks*4+g) ^ (s & 7)) << 3)];
    pB[ks] = &Bs[(wc*64  + s)*64 + (((ks*4+g) ^ (s & 7)) << 3)];
  }

  f32x4 acc[8][4];
#pragma unroll
  for (int i=0;i<8;i++)
#pragma unroll
    for (int j=0;j<4;j++) acc[i][j] = (f32x4){0.f,0.f,0.f,0.f};

#define PSTAGE_A(buf, TCE, h) do { \
    gload16(Ak + offA[h][0] + (TCE), &As[(buf)*16384 + (h)*8192 + (w*64)*8]); \
    gload16(Ak + offA[h][1] + (TCE), &As[(buf)*16384 + (h)*8192 + (512 + w*64)*8]); \
  } while(0)

#define PSTAGE_B(buf, TCE, h) do { \
    gload16(Wk + offB[h][0] + (TCE), &Bs[(buf)*16384 + (h)*8192 + (w*64)*8]); \
    gload16(Wk + offB[h][1] + (TCE), &Bs[(buf)*16384 + (h)*8192 + (512 + w*64)*8]); \
  } while(0)

#define PLOADA(cb, mh) do { \
    _Pragma("unroll") for (int mi2=0; mi2<4; mi2++) \
    _Pragma("unroll") for (int ks=0; ks<2; ks++) \
      af[mi2][ks] = *(const bf16x8*)(pA[ks] + (cb)*16384 + (mh)*4096 + mi2*1024); \
    } while(0)

#define PLOADB(dst, cb, nh) do { \
    _Pragma("unroll") for (int ni2=0; ni2<2; ni2++) \
    _Pragma("unroll") for (int ks=0; ks<2; ks++) \
      dst[ni2][ks] = *(const bf16x8*)(pB[ks] + (cb)*16384 + (nh)*2048 + ni2*1024); \
    } while(0)

#define PMFMA(mh, nh, bfr) do { \
    _Pragma("unroll") for (int mi2=0; mi2<4; mi2++) \
    _Pragma("unroll") for (int ni2=0; ni2<2; ni2++) \
    _Pragma("unroll") for (int ks=0; ks<2; ks++) \
      acc[(mh)*4+mi2][(nh)*2+ni2] = __builtin_amdgcn_mfma_f32_16x16x32_bf16( \
          af[mi2][ks], bfr[ni2][ks], acc[(mh)*4+mi2][(nh)*2+ni2], 0, 0, 0); \
    } while(0)

#define BAR   __builtin_amdgcn_s_barrier()
#define PRIO1 __builtin_amdgcn_s_setprio(1)
#define PRIO0 __builtin_amdgcn_s_setprio(0)

  {
    const u16* Ak = A;  const u16* Wk = wall;
    PSTAGE_A(0, 0, 0); PSTAGE_A(0, 0, 1); PSTAGE_B(0, 0, 0); PSTAGE_B(0, 0, 1);
    PSTAGE_B(1, 64, 0); PSTAGE_B(1, 64, 1);
  }
  asm volatile("s_waitcnt vmcnt(4)" ::: "memory");
  BAR;

#pragma unroll 1
  for (int it = 0; it < 8; ++it){
    const u16* Ak = A + it*128;
    const u16* Wk = wall + it*128;
    const bool pre = (it < 7);
    {
      bf16x8 af[4][2], bf0[2][2], bf1[2][2];
      PSTAGE_A(1, 64, 0);
      PLOADA(0, 0); PLOADB(bf0, 0, 0);
      PRIO1; PMFMA(0, 0, bf0); PRIO0; BAR;
      PSTAGE_A(1, 64, 1);
      PLOADB(bf1, 0, 1);
      PRIO1; PMFMA(0, 1, bf1); PRIO0; BAR;
      if (pre) PSTAGE_B(0, 128, 0);
      PLOADA(0, 1);
      PRIO1; PMFMA(1, 1, bf1); PRIO0; BAR;
      if (pre) PSTAGE_B(0, 128, 1);
      PRIO1; PMFMA(1, 0, bf0); PRIO0;
      if (it == 7) asm volatile("s_waitcnt vmcnt(0)" ::: "memory");
      else         asm volatile("s_waitcnt vmcnt(4)" ::: "memory");
      BAR;
    }
    {
      bf16x8 af[4][2], bf0[2][2], bf1[2][2];
      if (pre) PSTAGE_A(0, 128, 0);
      PLOADA(1, 0); PLOADB(bf0, 1, 0);
      PRIO1; PMFMA(0, 0, bf0); PRIO0; BAR;
      if (pre) PSTAGE_A(0, 128, 1);
      PLOADB(bf1, 1, 1);
      PRIO1; PMFMA(0, 1, bf1); PRIO0; BAR;
      if (pre) PSTAGE_B(1, 192, 0);
      PLOADA(1, 1);
      PRIO1; PMFMA(1, 1, bf1); PRIO0; BAR;
      if (pre) PSTAGE_B(1, 192, 1);
      PRIO1; PMFMA(1, 0, bf0); PRIO0;
      asm volatile("s_waitcnt vmcnt(4)" ::: "memory");
      BAR;
    }
  }

  const float* bias = (chunk==0)?bqp:(chunk==1)?brp:(chunk==2)?bkp:bvp;
  u16* outp = (chunk==0)?qpj:(chunk==1)?rpj:kpj;
#pragma unroll
  for (int ni=0; ni<4; ni++){
    int cg = ng0 + wc*64 + ni*16 + s;
    int col = cg & 1023;
    float bv = bias[col];
#pragma unroll
    for (int mi=0; mi<8; mi++){
      int row = m0 + wr*128 + mi*16 + g*4;
      if (chunk == 3){
        union { short4 v; u16 e[4]; } pk2;
#pragma unroll
        for (int r=0;r<4;r++) pk2.e[r] = f2bf(acc[mi][ni][r] + bv);
        size_t vrow = ((size_t)(row >> 10) * 16 + (col >> 6)) * 64 + (col & 63);
        *(short4*)&vtg[(vrow << 10) + (row & 1023)] = pk2.v;
      } else {
#pragma unroll
        for (int r=0;r<4;r++)
          outp[((size_t)(row+r) << 10) + col] = f2bf(acc[mi][ni][r] + bv);
      }
    }
  }
#undef PSTAGE_A
#undef PSTAGE_B
#undef PLOADA
#undef PLOADB
#undef PMFMA
#undef BAR
#undef PRIO1
#undef PRIO0
}

// ---------------- output GEMM: Out[M][1024] = A @ Bt^T + bias (f32 out) ----------------
__global__ __launch_bounds__(256) void k_gemm_out(const u16* __restrict__ A, const u16* __restrict__ Bt,
                                                  const float* __restrict__ bias, float* __restrict__ Out){
  __shared__ u16 As[128*64];
  __shared__ u16 Bs[128*64];
  const int tid = threadIdx.x;
  const int w = tid >> 6, l = tid & 63, g = l >> 4, s = l & 15;
  const int wr = w >> 1, wc = w & 1;
  const int m0 = blockIdx.x << 7, n0 = blockIdx.y << 7;
  f32x4 acc[4][4];
#pragma unroll
  for (int i=0;i<4;i++)
#pragma unroll
    for (int j=0;j<4;j++) acc[i][j] = (f32x4){0.f,0.f,0.f,0.f};

  for (int k0 = 0; k0 < 1024; k0 += 64){
    __syncthreads();
#pragma unroll
    for (int i=0;i<4;i++){
      int c = tid + i*256;
      int m = c >> 3, slot = c & 7;
      gload16(A + ((size_t)(m0+m) << 10) + (k0 + ((slot ^ (m & 7)) << 3)),
              &As[(i*256 + w*64) * 8]);
    }
#pragma unroll
    for (int i=0;i<4;i++){
      int c = tid + i*256;
      int n = c >> 3, slot = c & 7;
      gload16(Bt + ((size_t)(n0+n) << 10) + (k0 + ((slot ^ (n & 7)) << 3)),
              &Bs[(i*256 + w*64) * 8]);
    }
    __syncthreads();
#pragma unroll
    for (int ks=0; ks<2; ks++){
      bf16x8 af[4], bfv[4];
#pragma unroll
      for (int mi=0;mi<4;mi++){
        int m = wr*64 + mi*16 + s;
        af[mi] = *(const bf16x8*)&As[m*64 + (((ks*4+g) ^ (s & 7)) << 3)];
      }
#pragma unroll
      for (int ni=0;ni<4;ni++){
        int n = wc*64 + ni*16 + s;
        bfv[ni] = *(const bf16x8*)&Bs[n*64 + (((ks*4+g) ^ (s & 7)) << 3)];
      }
#pragma unroll
      for (int mi=0;mi<4;mi++)
#pragma unroll
        for (int ni=0;ni<4;ni++)
          acc[mi][ni] = __builtin_amdgcn_mfma_f32_16x16x32_bf16(af[mi], bfv[ni], acc[mi][ni], 0, 0, 0);
    }
  }
#pragma unroll
  for (int ni=0;ni<4;ni++){
    int col = n0 + wc*64 + ni*16 + s;
    float bv = bias[col];
#pragma unroll
    for (int mi=0;mi<4;mi++){
      int row = m0 + wr*64 + mi*16 + g*4;
#pragma unroll
      for (int r=0;r<4;r++)
        Out[((size_t)(row+r) << 10) + col] = acc[mi][ni][r] + bv;
    }
  }
}

// ------- flash attention + R-gating: QBLK=256 via 16 waves x 16 rows (round-8 per-wave code) -------
// grid: 512 1-D (XCD-swizzled). block 1024. Waves 0-7 stage K, 8-15 stage V (1 load/thread).
__global__ __launch_bounds__(1024, 8) void k_attn(const u16* __restrict__ qp, const u16* __restrict__ kp,
                                                  const u16* __restrict__ vtg, const u16* __restrict__ rp,
                                                  u16* __restrict__ gated){
  extern __shared__ u16 asmem[];
  u16* KsB = asmem;                      // [2][4096] u16 (16 KB)
  u16* VsB = asmem + 8192;               // [2][4096] u16 (16 KB)
  u32* PsU = (u32*)(asmem + 16384);      // [16][512] u32 (32 KB)
  const int tid = threadIdx.x;
  const int w = tid >> 6, l = tid & 63, g = l >> 4, s = l & 15;
  const int bid = blockIdx.x;
  const int swz = (bid & 7) * 64 + (bid >> 3);   // XCD-bijective (512 % 8 == 0)
  const int bh = swz >> 2;
  const int q0 = (swz & 3) << 8;
  const int b = bh >> 4, h = bh & 15;
  const size_t base = ((size_t)b << 20);
  const int colh = h << 6;
  const float KL = 1.4426950408889634f / 32.0f;

  const size_t qoff = base + ((size_t)(q0 + w*16 + s) << 10) + colh;
  bf16x8 qf0 = *(const bf16x8*)(qp + qoff + g*8);
  bf16x8 qf1 = *(const bf16x8*)(qp + qoff + 32 + g*8);
  const size_t vbase = ((size_t)(b*16 + h)) << 16;

  u32* PsW = PsU + (w << 9);
  const int sx2 = s << 1;

  // staging offsets: tl in [0,512): rr = row of 64-row tile, sl = 16B slot (involution swizzle)
  const int tl = tid & 511;
  const int rr = tl >> 3, sl = tl & 7;
  const u32 koff = (u32)(rr << 10) + colh + ((sl ^ (rr & 7)) << 3);
  const u32 voff = (u32)(rr << 10) + ((sl ^ (rr & 7)) << 3);
  const u16* kbgl = kp + base;
  const u16* vbgl = vtg + vbase;

  float mrun = -1e30f, lsum = 0.f;
  f32x4 of[4];
#pragma unroll
  for (int d=0;d<4;d++) of[d] = (f32x4){0.f,0.f,0.f,0.f};

#define STAGE_KV(BUF, KV0) do { \
    if (w < 8) gload16(kbgl + ((u32)(KV0) << 10) + koff, KsB + (BUF)*4096 + w*512); \
    else       gload16(vbgl + (KV0) + voff, VsB + (BUF)*4096 + (w - 8)*512); \
  } while(0)

  STAGE_KV(0, 0);
  __syncthreads();

  int cur = 0;
  for (int t = 0; t < 16; t++){
    if (t < 15) STAGE_KV(cur ^ 1, (t+1) << 6);
    const u16* ksb = KsB + cur*4096;
    const u16* vsb = VsB + cur*4096;

    f32x4 e2[4];
#pragma unroll
    for (int sjf=0;sjf<4;sjf++){
      e2[sjf] = (f32x4){0.f,0.f,0.f,0.f};
      int sj = sjf*16 + s;
      bf16x8 kf0 = *(const bf16x8*)&ksb[sj*64 + ((g ^ (s & 7)) << 3)];
      e2[sjf] = __builtin_amdgcn_mfma_f32_16x16x32_bf16(kf0, qf0, e2[sjf], 0, 0, 0);
      bf16x8 kf1 = *(const bf16x8*)&ksb[sj*64 + (((4+g) ^ (s & 7)) << 3)];
      e2[sjf] = __builtin_amdgcn_mfma_f32_16x16x32_bf16(kf1, qf1, e2[sjf], 0, 0, 0);
    }
    float rm = fmaxf(fmaxf(e2[0][0], e2[0][1]), e2[0][2]);
    rm = fmaxf(fmaxf(rm, e2[0][3]), e2[1][0]);
    rm = fmaxf(fmaxf(rm, e2[1][1]), e2[1][2]);
    rm = fmaxf(fmaxf(rm, e2[1][3]), e2[2][0]);
    rm = fmaxf(fmaxf(rm, e2[2][1]), e2[2][2]);
    rm = fmaxf(fmaxf(rm, e2[2][3]), e2[3][0]);
    rm = fmaxf(fmaxf(rm, e2[3][1]), e2[3][2]);
    rm = fmaxf(rm, e2[3][3]);
    rm = fmaxf(rm, __shfl_xor(rm, 16, 64));
    rm = fmaxf(rm, __shfl_xor(rm, 32, 64));
    if (!__all(rm <= mrun + 177.0f)){
      float nm = fmaxf(mrun, rm);
      float alpha = __builtin_amdgcn_exp2f((mrun - nm) * KL);
      mrun = nm;
      lsum *= alpha;
      float ac[4];
#pragma unroll
      for (int r=0;r<4;r++) ac[r] = __shfl(alpha, g*4 + r, 64);
#pragma unroll
      for (int d=0; d<4; d++)
#pragma unroll
        for (int r=0;r<4;r++) of[d][r] *= ac[r];
    }

    const float mk = mrun * KL;
#pragma unroll
    for (int sjf=0;sjf<4;sjf++){
      float p0 = __builtin_amdgcn_exp2f(e2[sjf][0]*KL - mk);
      float p1 = __builtin_amdgcn_exp2f(e2[sjf][1]*KL - mk);
      float p2 = __builtin_amdgcn_exp2f(e2[sjf][2]*KL - mk);
      float p3 = __builtin_amdgcn_exp2f(e2[sjf][3]*KL - mk);
      lsum += (p0 + p1) + (p2 + p3);
      uint2 pk; pk.x = cvtpk(p0, p1); pk.y = cvtpk(p2, p3);
      int phys = (8*sjf + 2*g) ^ sx2;
      *reinterpret_cast<uint2*>(&PsW[(s << 5) + phys]) = pk;
    }
    union { u32 u[4]; bf16x8 v; } pa0, pa1;
    {
      uint2 r0 = *reinterpret_cast<const uint2*>(&PsW[(s << 5) + ((4*g    ) ^ sx2)]);
      uint2 r1 = *reinterpret_cast<const uint2*>(&PsW[(s << 5) + ((4*g + 2) ^ sx2)]);
      pa0.u[0] = r0.x; pa0.u[1] = r0.y; pa0.u[2] = r1.x; pa0.u[3] = r1.y;
      uint2 r2 = *reinterpret_cast<const uint2*>(&PsW[(s << 5) + ((16 + 4*g    ) ^ sx2)]);
      uint2 r3 = *reinterpret_cast<const uint2*>(&PsW[(s << 5) + ((16 + 4*g + 2) ^ sx2)]);
      pa1.u[0] = r2.x; pa1.u[1] = r2.y; pa1.u[2] = r3.x; pa1.u[3] = r3.y;
    }
#pragma unroll
    for (int df=0; df<4; df++){
      int d = df*16 + s;
      bf16x8 v0 = *(const bf16x8*)&vsb[d*64 + ((g ^ (s & 7)) << 3)];
      bf16x8 v1 = *(const bf16x8*)&vsb[d*64 + (((4+g) ^ (s & 7)) << 3)];
      of[df] = __builtin_amdgcn_mfma_f32_16x16x32_bf16(pa0.v, v0, of[df], 0, 0, 0);
      of[df] = __builtin_amdgcn_mfma_f32_16x16x32_bf16(pa1.v, v1, of[df], 0, 0, 0);
    }
    __syncthreads();
    cur ^= 1;
  }
#undef STAGE_KV

  lsum += __shfl_xor(lsum, 16, 64);
  lsum += __shfl_xor(lsum, 32, 64);
  float inv = 1.0f / lsum;
  float ic[4];
#pragma unroll
  for (int r=0;r<4;r++) ic[r] = __shfl(inv, g*4 + r, 64);
#pragma unroll
  for (int df=0; df<4; df++){
#pragma unroll
    for (int r=0;r<4;r++){
      size_t row = (size_t)(q0 + w*16 + g*4 + r);
      size_t idx = base + (row << 10) + colh + df*16 + s;
      float o = of[df][r] * ic[r];
      float rg = bf2f(rp[idx]);
      gated[idx] = f2bf(o * rg);
    }
  }
}

extern "C" void kernel_launch(void* const* d_in, const int* in_sizes, int n_in,
                              void* d_out, int out_size, void* d_ws, size_t ws_size,
                              hipStream_t stream){
  (void)in_sizes; (void)n_in; (void)out_size; (void)ws_size;
  const float* value = (const float*)d_in[0];
  const float* key   = (const float*)d_in[1];
  const float* query = (const float*)d_in[2];
  const float* Wq = (const float*)d_in[3];  const float* bq = (const float*)d_in[4];
  const float* Wk = (const float*)d_in[5];  const float* bk = (const float*)d_in[6];
  const float* Wv = (const float*)d_in[7];  const float* bv = (const float*)d_in[8];
  const float* Wr = (const float*)d_in[9];  const float* br = (const float*)d_in[10];
  const float* Wo = (const float*)d_in[11]; const float* bo = (const float*)d_in[12];

  char* ws = (char*)d_ws;
  const size_t MB = (size_t)1 << 20;
  u16* qb   = (u16*)(ws + 0*MB);
  u16* kb   = (u16*)(ws + 16*MB);
  u16* vb   = (u16*)(ws + 32*MB);
  u16* wall = (u16*)(ws + 48*MB);    // 8 MB: [Wq^T | Wr^T | Wk^T | Wv^T] bf16 [4096][1024]
  u16* wot  = (u16*)(ws + 56*MB);
  u16* qpj  = (u16*)(ws + 58*MB);
  u16* kpj  = (u16*)(ws + 74*MB);
  u16* vtg  = (u16*)(ws + 90*MB);    // V projection, pre-transposed [(b*16+h)*64+d][sq]
  u16* rpj  = (u16*)(ws + 106*MB);
  u16* gat  = qb;

  (void)hipFuncSetAttribute(reinterpret_cast<const void*>(&k_proj8),
                            hipFuncAttributeMaxDynamicSharedMemorySize, 131072);
  (void)hipFuncSetAttribute(reinterpret_cast<const void*>(&k_attn),
                            hipFuncAttributeMaxDynamicSharedMemorySize, 65536);

  k_cvt_act<<<dim3(4096, 3), 256, 0, stream>>>(value, key, query, vb, kb, qb);
  k_cvt_wt<<<dim3(32, 32, 5), dim3(32, 8), 0, stream>>>(Wq, Wr, Wk, Wv, Wo, wall, wot);
  k_proj8<<<dim3(32, 16), 512, 131072, stream>>>(qb, kb, vb, wall, bq, br, bk, bv,
                                                 qpj, rpj, kpj, vtg);
  k_attn<<<512, 1024, 65536, stream>>>(qpj, kpj, vtg, rpj, gat);
  k_gemm_out<<<dim3(64, 8), 256, 0, stream>>>(gat, wot, bo, (float*)d_out);
}

// Round 14
// 188.832 us; speedup vs baseline: 1.7470x; 1.0920x over previous
//
#include <hip/hip_runtime.h>
#include <stdint.h>

#define B_ 8
#define S_ 1024
#define DM_ 1024
#define H_ 16
#define DH_ 64
#define M_ (B_*S_)

typedef unsigned short u16;
typedef unsigned int u32;
typedef __attribute__((ext_vector_type(8))) short bf16x8;
typedef __attribute__((ext_vector_type(4))) float f32x4;

__device__ __forceinline__ u16 f2bf(float f){
  union { float f; u32 u; } x; x.f = f;
  u32 r = x.u + 0x7fffu + ((x.u >> 16) & 1u);
  return (u16)(r >> 16);
}
__device__ __forceinline__ float bf2f(u16 u){
  union { u32 u; float f; } x; x.u = ((u32)u) << 16; return x.f;
}
__device__ __forceinline__ u32 cvtpk(float lo, float hi){
  u32 r; asm("v_cvt_pk_bf16_f32 %0, %1, %2" : "=v"(r) : "v"(lo), "v"(hi)); return r;
}
__device__ __forceinline__ void gload16(const void* g, void* l){
  __builtin_amdgcn_global_load_lds((const __attribute__((address_space(1))) void*)g,
                                   (__attribute__((address_space(3))) void*)l, 16, 0, 0);
}

// ---------------- convert activations fp32 -> bf16 ----------------
__global__ void k_cvt_act(const float* __restrict__ v, const float* __restrict__ k,
                          const float* __restrict__ q, u16* __restrict__ vb,
                          u16* __restrict__ kb, u16* __restrict__ qb){
  int z = blockIdx.y;
  const float* src = (z == 0) ? v : (z == 1) ? k : q;
  u16* dst = (z == 0) ? vb : (z == 1) ? kb : qb;
  size_t i = ((size_t)blockIdx.x * blockDim.x + threadIdx.x) * 8;
  float4 a = *(const float4*)(src + i);
  float4 b = *(const float4*)(src + i + 4);
  uint4 o;
  o.x = (u32)f2bf(a.x) | ((u32)f2bf(a.y) << 16);
  o.y = (u32)f2bf(a.z) | ((u32)f2bf(a.w) << 16);
  o.z = (u32)f2bf(b.x) | ((u32)f2bf(b.y) << 16);
  o.w = (u32)f2bf(b.z) | ((u32)f2bf(b.w) << 16);
  *(uint4*)(dst + i) = o;
}

// -------- convert + transpose weights fp32[K][N] -> bf16[N][K]; z<4 into wall chunks --------
__global__ void k_cvt_wt(const float* __restrict__ w0, const float* __restrict__ w1,
                         const float* __restrict__ w2, const float* __restrict__ w3,
                         const float* __restrict__ w4,
                         u16* __restrict__ wall, u16* __restrict__ wot){
  __shared__ float tile[32][33];
  int z = blockIdx.z;
  const float* src = (z==0)?w0:(z==1)?w1:(z==2)?w2:(z==3)?w3:w4;
  u16* dst = (z<4) ? (wall + (size_t)z * 1048576) : wot;
  int n0 = blockIdx.x * 32, k0 = blockIdx.y * 32;
  int tx = threadIdx.x, ty = threadIdx.y;
#pragma unroll
  for (int i=0;i<4;i++) tile[ty+8*i][tx] = src[(size_t)(k0+ty+8*i)*DM_ + n0+tx];
  __syncthreads();
#pragma unroll
  for (int i=0;i<4;i++) dst[(size_t)(n0+ty+8*i)*DM_ + k0+tx] = f2bf(tile[tx][ty+8*i]);
}

// ======== fused projection GEMM, 256x256 tile, BK=64, 8-phase, ONE barrier per phase ========
// (Round-8 version — measured 85.9 us; schedule variants all null/regressed.)
__global__ __launch_bounds__(512, 2) void k_proj8(const u16* __restrict__ qb, const u16* __restrict__ kb,
                                                  const u16* __restrict__ vb, const u16* __restrict__ wall,
                                                  const float* __restrict__ bqp, const float* __restrict__ brp,
                                                  const float* __restrict__ bkp, const float* __restrict__ bvp,
                                                  u16* __restrict__ qpj, u16* __restrict__ rpj,
                                                  u16* __restrict__ kpj, u16* __restrict__ vtg){
  extern __shared__ u16 smem[];
  u16* As = smem;                 // [2][2][128][64]  (buf, half)
  u16* Bs = smem + 32768;         // [2][2][128][64]
  const int tid = threadIdx.x;
  const int w = tid >> 6, l = tid & 63, g = l >> 4, s = l & 15;
  const int wr = w >> 2, wc = w & 3;
  const int m0 = blockIdx.x << 8;
  const int ng0 = blockIdx.y << 8;
  const int chunk = ng0 >> 10;
  const u16* A = (chunk < 2) ? qb : (chunk == 2) ? kb : vb;

  u32 offA[2][2], offB[2][2];   // [half][i2]
#pragma unroll
  for (int h=0; h<2; h++)
#pragma unroll
    for (int i2=0; i2<2; i2++){
      int c = tid + i2*512; int rw = c >> 3, sl = c & 7;
      offA[h][i2] = (u32)((m0  + h*128 + rw) << 10) + ((sl ^ (rw & 7)) << 3);
      offB[h][i2] = (u32)((ng0 + h*128 + rw) << 10) + ((sl ^ (rw & 7)) << 3);
    }
  const u16* pA[2]; const u16* pB[2];
#pragma unroll
  for (int ks=0; ks<2; ks++){
    pA[ks] = &As[(wr*128 + s)*64 + (((ks*4+g) ^ (s & 7)) << 3)];
    pB[ks] = &Bs[(wc*64  + s)*64 + (((ks*4+g) ^ (s & 7)) << 3)];
  }

  f32x4 acc[8][4];
#pragma unroll
  for (int i=0;i<8;i++)
#pragma unroll
    for (int j=0;j<4;j++) acc[i][j] = (f32x4){0.f,0.f,0.f,0.f};

#define PSTAGE_A(buf, TCE, h) do { \
    gload16(Ak + offA[h][0] + (TCE), &As[(buf)*16384 + (h)*8192 + (w*64)*8]); \
    gload16(Ak + offA[h][1] + (TCE), &As[(buf)*16384 + (h)*8192 + (512 + w*64)*8]); \
  } while(0)

#define PSTAGE_B(buf, TCE, h) do { \
    gload16(Wk + offB[h][0] + (TCE), &Bs[(buf)*16384 + (h)*8192 + (w*64)*8]); \
    gload16(Wk + offB[h][1] + (TCE), &Bs[(buf)*16384 + (h)*8192 + (512 + w*64)*8]); \
  } while(0)

#define PLOADA(cb, mh) do { \
    _Pragma("unroll") for (int mi2=0; mi2<4; mi2++) \
    _Pragma("unroll") for (int ks=0; ks<2; ks++) \
      af[mi2][ks] = *(const bf16x8*)(pA[ks] + (cb)*16384 + (mh)*4096 + mi2*1024); \
    } while(0)

#define PLOADB(dst, cb, nh) do { \
    _Pragma("unroll") for (int ni2=0; ni2<2; ni2++) \
    _Pragma("unroll") for (int ks=0; ks<2; ks++) \
      dst[ni2][ks] = *(const bf16x8*)(pB[ks] + (cb)*16384 + (nh)*2048 + ni2*1024); \
    } while(0)

#define PMFMA(mh, nh, bfr) do { \
    _Pragma("unroll") for (int mi2=0; mi2<4; mi2++) \
    _Pragma("unroll") for (int ni2=0; ni2<2; ni2++) \
    _Pragma("unroll") for (int ks=0; ks<2; ks++) \
      acc[(mh)*4+mi2][(nh)*2+ni2] = __builtin_amdgcn_mfma_f32_16x16x32_bf16( \
          af[mi2][ks], bfr[ni2][ks], acc[(mh)*4+mi2][(nh)*2+ni2], 0, 0, 0); \
    } while(0)

#define BAR   __builtin_amdgcn_s_barrier()
#define PRIO1 __builtin_amdgcn_s_setprio(1)
#define PRIO0 __builtin_amdgcn_s_setprio(0)

  {
    const u16* Ak = A;  const u16* Wk = wall;
    PSTAGE_A(0, 0, 0); PSTAGE_A(0, 0, 1); PSTAGE_B(0, 0, 0); PSTAGE_B(0, 0, 1);
    PSTAGE_B(1, 64, 0); PSTAGE_B(1, 64, 1);
  }
  asm volatile("s_waitcnt vmcnt(4)" ::: "memory");
  BAR;

#pragma unroll 1
  for (int it = 0; it < 8; ++it){
    const u16* Ak = A + it*128;
    const u16* Wk = wall + it*128;
    const bool pre = (it < 7);
    {
      bf16x8 af[4][2], bf0[2][2], bf1[2][2];
      PSTAGE_A(1, 64, 0);
      PLOADA(0, 0); PLOADB(bf0, 0, 0);
      PRIO1; PMFMA(0, 0, bf0); PRIO0; BAR;
      PSTAGE_A(1, 64, 1);
      PLOADB(bf1, 0, 1);
      PRIO1; PMFMA(0, 1, bf1); PRIO0; BAR;
      if (pre) PSTAGE_B(0, 128, 0);
      PLOADA(0, 1);
      PRIO1; PMFMA(1, 1, bf1); PRIO0; BAR;
      if (pre) PSTAGE_B(0, 128, 1);
      PRIO1; PMFMA(1, 0, bf0); PRIO0;
      if (it == 7) asm volatile("s_waitcnt vmcnt(0)" ::: "memory");
      else         asm volatile("s_waitcnt vmcnt(4)" ::: "memory");
      BAR;
    }
    {
      bf16x8 af[4][2], bf0[2][2], bf1[2][2];
      if (pre) PSTAGE_A(0, 128, 0);
      PLOADA(1, 0); PLOADB(bf0, 1, 0);
      PRIO1; PMFMA(0, 0, bf0); PRIO0; BAR;
      if (pre) PSTAGE_A(0, 128, 1);
      PLOADB(bf1, 1, 1);
      PRIO1; PMFMA(0, 1, bf1); PRIO0; BAR;
      if (pre) PSTAGE_B(1, 192, 0);
      PLOADA(1, 1);
      PRIO1; PMFMA(1, 1, bf1); PRIO0; BAR;
      if (pre) PSTAGE_B(1, 192, 1);
      PRIO1; PMFMA(1, 0, bf0); PRIO0;
      asm volatile("s_waitcnt vmcnt(4)" ::: "memory");
      BAR;
    }
  }

  const float* bias = (chunk==0)?bqp:(chunk==1)?brp:(chunk==2)?bkp:bvp;
  u16* outp = (chunk==0)?qpj:(chunk==1)?rpj:kpj;
#pragma unroll
  for (int ni=0; ni<4; ni++){
    int cg = ng0 + wc*64 + ni*16 + s;
    int col = cg & 1023;
    float bv = bias[col];
#pragma unroll
    for (int mi=0; mi<8; mi++){
      int row = m0 + wr*128 + mi*16 + g*4;
      if (chunk == 3){
        union { short4 v; u16 e[4]; } pk2;
#pragma unroll
        for (int r=0;r<4;r++) pk2.e[r] = f2bf(acc[mi][ni][r] + bv);
        size_t vrow = ((size_t)(row >> 10) * 16 + (col >> 6)) * 64 + (col & 63);
        *(short4*)&vtg[(vrow << 10) + (row & 1023)] = pk2.v;
      } else {
#pragma unroll
        for (int r=0;r<4;r++)
          outp[((size_t)(row+r) << 10) + col] = f2bf(acc[mi][ni][r] + bv);
      }
    }
  }
#undef PSTAGE_A
#undef PSTAGE_B
#undef PLOADA
#undef PLOADB
#undef PMFMA
#undef BAR
#undef PRIO1
#undef PRIO0
}

// ---------------- output GEMM: Out[M][1024] = A @ Bt^T + bias (f32 out) ----------------
__global__ __launch_bounds__(256) void k_gemm_out(const u16* __restrict__ A, const u16* __restrict__ Bt,
                                                  const float* __restrict__ bias, float* __restrict__ Out){
  __shared__ u16 As[128*64];
  __shared__ u16 Bs[128*64];
  const int tid = threadIdx.x;
  const int w = tid >> 6, l = tid & 63, g = l >> 4, s = l & 15;
  const int wr = w >> 1, wc = w & 1;
  const int m0 = blockIdx.x << 7, n0 = blockIdx.y << 7;
  f32x4 acc[4][4];
#pragma unroll
  for (int i=0;i<4;i++)
#pragma unroll
    for (int j=0;j<4;j++) acc[i][j] = (f32x4){0.f,0.f,0.f,0.f};

  for (int k0 = 0; k0 < 1024; k0 += 64){
    __syncthreads();
#pragma unroll
    for (int i=0;i<4;i++){
      int c = tid + i*256;
      int m = c >> 3, slot = c & 7;
      gload16(A + ((size_t)(m0+m) << 10) + (k0 + ((slot ^ (m & 7)) << 3)),
              &As[(i*256 + w*64) * 8]);
    }
#pragma unroll
    for (int i=0;i<4;i++){
      int c = tid + i*256;
      int n = c >> 3, slot = c & 7;
      gload16(Bt + ((size_t)(n0+n) << 10) + (k0 + ((slot ^ (n & 7)) << 3)),
              &Bs[(i*256 + w*64) * 8]);
    }
    __syncthreads();
#pragma unroll
    for (int ks=0; ks<2; ks++){
      bf16x8 af[4], bfv[4];
#pragma unroll
      for (int mi=0;mi<4;mi++){
        int m = wr*64 + mi*16 + s;
        af[mi] = *(const bf16x8*)&As[m*64 + (((ks*4+g) ^ (s & 7)) << 3)];
      }
#pragma unroll
      for (int ni=0;ni<4;ni++){
        int n = wc*64 + ni*16 + s;
        bfv[ni] = *(const bf16x8*)&Bs[n*64 + (((ks*4+g) ^ (s & 7)) << 3)];
      }
#pragma unroll
      for (int mi=0;mi<4;mi++)
#pragma unroll
        for (int ni=0;ni<4;ni++)
          acc[mi][ni] = __builtin_amdgcn_mfma_f32_16x16x32_bf16(af[mi], bfv[ni], acc[mi][ni], 0, 0, 0);
    }
  }
#pragma unroll
  for (int ni=0;ni<4;ni++){
    int col = n0 + wc*64 + ni*16 + s;
    float bv = bias[col];
#pragma unroll
    for (int mi=0;mi<4;mi++){
      int row = m0 + wr*64 + mi*16 + g*4;
#pragma unroll
      for (int r=0;r<4;r++)
        Out[((size_t)(row+r) << 10) + col] = acc[mi][ni][r] + bv;
    }
  }
}

// ------- flash attention + R-gating: QBLK=128 (8 waves), swapped QK^T, dbuf, defer-max -------
// (Round-8 version verbatim — best passing configuration.)
__global__ __launch_bounds__(512) void k_attn(const u16* __restrict__ qp, const u16* __restrict__ kp,
                                              const u16* __restrict__ vtg, const u16* __restrict__ rp,
                                              u16* __restrict__ gated){
  __shared__ u16 Ks[2][64*64];     // [sj][d], k-slot XOR-swizzled
  __shared__ u16 Vs[2][64*64];     // [d][sj], sj-slot XOR-swizzled
  __shared__ u32 PsU[8*16*32];     // per-wave P rows, XOR-banked
  const int tid = threadIdx.x;
  const int w = tid >> 6, l = tid & 63, g = l >> 4, s = l & 15;
  const int bid = blockIdx.x;
  const int swz = (bid & 7) * 128 + (bid >> 3);   // XCD-bijective (1024 % 8 == 0)
  const int bh = swz >> 3;
  const int q0 = (swz & 7) << 7;
  const int b = bh >> 4, h = bh & 15;
  const size_t base = ((size_t)b << 20);
  const int colh = h << 6;
  const float KL = 1.4426950408889634f / 32.0f;

  const size_t qoff = base + ((size_t)(q0 + w*16 + s) << 10) + colh;
  bf16x8 qf0 = *(const bf16x8*)(qp + qoff + g*8);
  bf16x8 qf1 = *(const bf16x8*)(qp + qoff + 32 + g*8);
  const size_t vbase = ((size_t)(b*16 + h)) << 16;

  u32* PsW = PsU + (w << 9);
  const int sx2 = s << 1;

  const int rr = tid >> 3, sl = tid & 7;
  const u32 koff = (u32)(rr << 10) + colh + ((sl ^ (rr & 7)) << 3);
  const u32 voff = (u32)(rr << 10) + ((sl ^ (rr & 7)) << 3);
  const u16* kbgl = kp + base;
  const u16* vbgl = vtg + vbase;

  float mrun = -1e30f, lsum = 0.f;
  f32x4 of[4];
#pragma unroll
  for (int d=0;d<4;d++) of[d] = (f32x4){0.f,0.f,0.f,0.f};

#define STAGE_KV(BUF, KV0) do { \
    gload16(kbgl + ((u32)(KV0) << 10) + koff, &Ks[BUF][(w*64)*8]); \
    gload16(vbgl + (KV0) + voff, &Vs[BUF][(w*64)*8]); \
  } while(0)

  STAGE_KV(0, 0);
  __syncthreads();

  int cur = 0;
  for (int t = 0; t < 16; t++){
    if (t < 15) STAGE_KV(cur ^ 1, (t+1) << 6);
    const u16* ksb = Ks[cur];
    const u16* vsb = Vs[cur];

    f32x4 e2[4];
#pragma unroll
    for (int sjf=0;sjf<4;sjf++){
      e2[sjf] = (f32x4){0.f,0.f,0.f,0.f};
      int sj = sjf*16 + s;
      bf16x8 kf0 = *(const bf16x8*)&ksb[sj*64 + ((g ^ (s & 7)) << 3)];
      e2[sjf] = __builtin_amdgcn_mfma_f32_16x16x32_bf16(kf0, qf0, e2[sjf], 0, 0, 0);
      bf16x8 kf1 = *(const bf16x8*)&ksb[sj*64 + (((4+g) ^ (s & 7)) << 3)];
      e2[sjf] = __builtin_amdgcn_mfma_f32_16x16x32_bf16(kf1, qf1, e2[sjf], 0, 0, 0);
    }
    float rm = fmaxf(fmaxf(e2[0][0], e2[0][1]), e2[0][2]);
    rm = fmaxf(fmaxf(rm, e2[0][3]), e2[1][0]);
    rm = fmaxf(fmaxf(rm, e2[1][1]), e2[1][2]);
    rm = fmaxf(fmaxf(rm, e2[1][3]), e2[2][0]);
    rm = fmaxf(fmaxf(rm, e2[2][1]), e2[2][2]);
    rm = fmaxf(fmaxf(rm, e2[2][3]), e2[3][0]);
    rm = fmaxf(fmaxf(rm, e2[3][1]), e2[3][2]);
    rm = fmaxf(rm, e2[3][3]);
    rm = fmaxf(rm, __shfl_xor(rm, 16, 64));
    rm = fmaxf(rm, __shfl_xor(rm, 32, 64));
    if (!__all(rm <= mrun + 177.0f)){
      float nm = fmaxf(mrun, rm);
      float alpha = __builtin_amdgcn_exp2f((mrun - nm) * KL);
      mrun = nm;
      lsum *= alpha;
      float ac[4];
#pragma unroll
      for (int r=0;r<4;r++) ac[r] = __shfl(alpha, g*4 + r, 64);
#pragma unroll
      for (int d=0; d<4; d++)
#pragma unroll
        for (int r=0;r<4;r++) of[d][r] *= ac[r];
    }

    const float mk = mrun * KL;
#pragma unroll
    for (int sjf=0;sjf<4;sjf++){
      float p0 = __builtin_amdgcn_exp2f(e2[sjf][0]*KL - mk);
      float p1 = __builtin_amdgcn_exp2f(e2[sjf][1]*KL - mk);
      float p2 = __builtin_amdgcn_exp2f(e2[sjf][2]*KL - mk);
      float p3 = __builtin_amdgcn_exp2f(e2[sjf][3]*KL - mk);
      lsum += (p0 + p1) + (p2 + p3);
      uint2 pk; pk.x = cvtpk(p0, p1); pk.y = cvtpk(p2, p3);
      int phys = (8*sjf + 2*g) ^ sx2;
      *reinterpret_cast<uint2*>(&PsW[(s << 5) + phys]) = pk;
    }
    union { u32 u[4]; bf16x8 v; } pa0, pa1;
    {
      uint2 r0 = *reinterpret_cast<const uint2*>(&PsW[(s << 5) + ((4*g    ) ^ sx2)]);
      uint2 r1 = *reinterpret_cast<const uint2*>(&PsW[(s << 5) + ((4*g + 2) ^ sx2)]);
      pa0.u[0] = r0.x; pa0.u[1] = r0.y; pa0.u[2] = r1.x; pa0.u[3] = r1.y;
      uint2 r2 = *reinterpret_cast<const uint2*>(&PsW[(s << 5) + ((16 + 4*g    ) ^ sx2)]);
      uint2 r3 = *reinterpret_cast<const uint2*>(&PsW[(s << 5) + ((16 + 4*g + 2) ^ sx2)]);
      pa1.u[0] = r2.x; pa1.u[1] = r2.y; pa1.u[2] = r3.x; pa1.u[3] = r3.y;
    }
#pragma unroll
    for (int df=0; df<4; df++){
      int d = df*16 + s;
      bf16x8 v0 = *(const bf16x8*)&vsb[d*64 + ((g ^ (s & 7)) << 3)];
      bf16x8 v1 = *(const bf16x8*)&vsb[d*64 + (((4+g) ^ (s & 7)) << 3)];
      of[df] = __builtin_amdgcn_mfma_f32_16x16x32_bf16(pa0.v, v0, of[df], 0, 0, 0);
      of[df] = __builtin_amdgcn_mfma_f32_16x16x32_bf16(pa1.v, v1, of[df], 0, 0, 0);
    }
    __syncthreads();
    cur ^= 1;
  }
#undef STAGE_KV

  lsum += __shfl_xor(lsum, 16, 64);
  lsum += __shfl_xor(lsum, 32, 64);
  float inv = 1.0f / lsum;
  float ic[4];
#pragma unroll
  for (int r=0;r<4;r++) ic[r] = __shfl(inv, g*4 + r, 64);
#pragma unroll
  for (int df=0; df<4; df++){
#pragma unroll
    for (int r=0;r<4;r++){
      size_t row = (size_t)(q0 + w*16 + g*4 + r);
      size_t idx = base + (row << 10) + colh + df*16 + s;
      float o = of[df][r] * ic[r];
      float rg = bf2f(rp[idx]);
      gated[idx] = f2bf(o * rg);
    }
  }
}

extern "C" void kernel_launch(void* const* d_in, const int* in_sizes, int n_in,
                              void* d_out, int out_size, void* d_ws, size_t ws_size,
                              hipStream_t stream){
  (void)in_sizes; (void)n_in; (void)out_size; (void)ws_size;
  const float* value = (const float*)d_in[0];
  const float* key   = (const float*)d_in[1];
  const float* query = (const float*)d_in[2];
  const float* Wq = (const float*)d_in[3];  const float* bq = (const float*)d_in[4];
  const float* Wk = (const float*)d_in[5];  const float* bk = (const float*)d_in[6];
  const float* Wv = (const float*)d_in[7];  const float* bv = (const float*)d_in[8];
  const float* Wr = (const float*)d_in[9];  const float* br = (const float*)d_in[10];
  const float* Wo = (const float*)d_in[11]; const float* bo = (const float*)d_in[12];

  char* ws = (char*)d_ws;
  const size_t MB = (size_t)1 << 20;
  u16* qb   = (u16*)(ws + 0*MB);
  u16* kb   = (u16*)(ws + 16*MB);
  u16* vb   = (u16*)(ws + 32*MB);
  u16* wall = (u16*)(ws + 48*MB);    // 8 MB: [Wq^T | Wr^T | Wk^T | Wv^T] bf16 [4096][1024]
  u16* wot  = (u16*)(ws + 56*MB);
  u16* qpj  = (u16*)(ws + 58*MB);
  u16* kpj  = (u16*)(ws + 74*MB);
  u16* vtg  = (u16*)(ws + 90*MB);    // V projection, pre-transposed [(b*16+h)*64+d][sq]
  u16* rpj  = (u16*)(ws + 106*MB);
  u16* gat  = qb;

  (void)hipFuncSetAttribute(reinterpret_cast<const void*>(&k_proj8),
                            hipFuncAttributeMaxDynamicSharedMemorySize, 131072);

  k_cvt_act<<<dim3(4096, 3), 256, 0, stream>>>(value, key, query, vb, kb, qb);
  k_cvt_wt<<<dim3(32, 32, 5), dim3(32, 8), 0, stream>>>(Wq, Wr, Wk, Wv, Wo, wall, wot);
  k_proj8<<<dim3(32, 16), 512, 131072, stream>>>(qb, kb, vb, wall, bq, br, bk, bv,
                                                 qpj, rpj, kpj, vtg);
  k_attn<<<1024, 512, 0, stream>>>(qpj, kpj, vtg, rpj, gat);
  k_gemm_out<<<dim3(64, 8), 256, 0, stream>>>(gat, wot, bo, (float*)d_out);
}